// Round 1
// baseline (416.323 us; speedup 1.0000x reference)
//
#include <hip/hip_runtime.h>
#include <math.h>

#define N      6144
#define NFEAT  128
#define HID    128
#define NHEADS 8
#define NCLASS 40
#define CAP    96        // ELL capacity per row; mean degree ~13, P(>96) ~ 0
#define EPS    1e-5f
#define ALPHA  0.2f

// ---------------------------------------------------------------- BN0
__global__ __launch_bounds__(256) void bn0_kernel(
    const float* __restrict__ x,
    const float* __restrict__ g, const float* __restrict__ b,
    const float* __restrict__ m, const float* __restrict__ v,
    float* __restrict__ xn) {
  int idx = blockIdx.x * 256 + threadIdx.x;
  if (idx >= N * NFEAT) return;
  int c = idx & (NFEAT - 1);
  float sc = g[c] * rsqrtf(v[c] + EPS);
  xn[idx] = (x[idx] - m[c]) * sc + b[c];
}

// ----------------------------------------------- ELL build from dense adj
__global__ __launch_bounds__(256) void build_ell(
    const float* __restrict__ adj,
    int* __restrict__ cols, float* __restrict__ vals, int* __restrict__ cnt) {
  __shared__ int scnt;
  const int i = blockIdx.x;
  if (threadIdx.x == 0) scnt = 0;
  __syncthreads();
  const float* row = adj + (size_t)i * N;
  for (int j = threadIdx.x; j < N; j += 256) {
    float a = row[j];
    if (a > 0.f) {
      int s = atomicAdd(&scnt, 1);
      if (s < CAP) {
        cols[(size_t)i * CAP + s] = j;
        vals[(size_t)i * CAP + s] = a;
      }
    }
  }
  __syncthreads();
  if (threadIdx.x == 0) cnt[i] = min(scnt, CAP);
}

// ------------------------------------- Wh[h] = xn @ W_att[h]  (fp32 GEMM)
// 64x64 tile, 256 threads, 4x4 micro-tile, BK=16, padded LDS (+4 keeps
// 16B alignment for float4 ds_read_b128 and breaks bank aliasing).
__global__ __launch_bounds__(256) void gemm_wh(
    const float* __restrict__ A,      // [N, NFEAT]
    const float* __restrict__ Wall,   // [NHEADS, NFEAT, HID]
    float* __restrict__ WhAll) {      // [NHEADS, N, HID]
  const int h  = blockIdx.z;
  const int bm = blockIdx.y * 64;
  const int bn = blockIdx.x * 64;
  const float* B = Wall + (size_t)h * NFEAT * HID;
  float* C = WhAll + (size_t)h * N * HID;

  __shared__ float As[16][68];
  __shared__ float Bs[16][68];

  const int tid = threadIdx.x;
  const int tx = tid & 15;       // col group
  const int ty = tid >> 4;       // row group
  float acc[4][4] = {{0.f}};

  for (int kb = 0; kb < NFEAT; kb += 16) {
    // stage A: rows bm..bm+63, k = kb..kb+15 (float4 per thread)
    {
      int am = tid >> 2;
      int aq = (tid & 3) * 4;
      float4 a4 = *(const float4*)(A + (size_t)(bm + am) * NFEAT + kb + aq);
      As[aq + 0][am] = a4.x;
      As[aq + 1][am] = a4.y;
      As[aq + 2][am] = a4.z;
      As[aq + 3][am] = a4.w;
      int bk = tid >> 4;
      int bnq = (tid & 15) * 4;
      float4 b4 = *(const float4*)(B + (size_t)(kb + bk) * HID + bn + bnq);
      *(float4*)&Bs[bk][bnq] = b4;
    }
    __syncthreads();
#pragma unroll
    for (int k = 0; k < 16; ++k) {
      float4 a4 = *(const float4*)&As[k][ty * 4];
      float4 b4 = *(const float4*)&Bs[k][tx * 4];
      acc[0][0] += a4.x * b4.x; acc[0][1] += a4.x * b4.y;
      acc[0][2] += a4.x * b4.z; acc[0][3] += a4.x * b4.w;
      acc[1][0] += a4.y * b4.x; acc[1][1] += a4.y * b4.y;
      acc[1][2] += a4.y * b4.z; acc[1][3] += a4.y * b4.w;
      acc[2][0] += a4.z * b4.x; acc[2][1] += a4.z * b4.y;
      acc[2][2] += a4.z * b4.z; acc[2][3] += a4.z * b4.w;
      acc[3][0] += a4.w * b4.x; acc[3][1] += a4.w * b4.y;
      acc[3][2] += a4.w * b4.z; acc[3][3] += a4.w * b4.w;
    }
    __syncthreads();
  }
#pragma unroll
  for (int i = 0; i < 4; ++i) {
    float4 o;
    o.x = acc[i][0]; o.y = acc[i][1]; o.z = acc[i][2]; o.w = acc[i][3];
    *(float4*)(C + (size_t)(bm + ty * 4 + i) * HID + bn + tx * 4) = o;
  }
}

// ------------------------------- s1[h,r] = Wh[h,r,:]·a_src[h]; s2 likewise
__global__ __launch_bounds__(256) void score_kernel(
    const float* __restrict__ Wh,
    const float* __restrict__ a_src, const float* __restrict__ a_dst,
    float* __restrict__ s1, float* __restrict__ s2) {
  int gw = (blockIdx.x * 256 + threadIdx.x) >> 6;   // global wave = (h, r)
  int lane = threadIdx.x & 63;
  int h = gw / N;
  int r = gw - h * N;
  const float* row = Wh + ((size_t)h * N + r) * HID;
  float2 wv = *(const float2*)(row + lane * 2);
  float2 uu = *(const float2*)(a_src + (size_t)h * HID + lane * 2);
  float2 dd = *(const float2*)(a_dst + (size_t)h * HID + lane * 2);
  float p1 = wv.x * uu.x + wv.y * uu.y;
  float p2 = wv.x * dd.x + wv.y * dd.y;
#pragma unroll
  for (int off = 32; off; off >>= 1) {
    p1 += __shfl_xor(p1, off, 64);
    p2 += __shfl_xor(p2, off, 64);
  }
  if (lane == 0) { s1[gw] = p1; s2[gw] = p2; }
}

// ---------------- attention softmax + aggregation + BN1 + ReLU -> xcat
// block = 128 threads = (i, h). Wave 0 computes edge weights lane-parallel;
// phase 2 accumulates over edges with coalesced Wh row loads.
__global__ __launch_bounds__(128) void attn_kernel(
    const float* __restrict__ Wh,
    const float* __restrict__ s1, const float* __restrict__ s2,
    const int* __restrict__ cols, const int* __restrict__ cnt,
    const float* __restrict__ g, const float* __restrict__ b,
    const float* __restrict__ m, const float* __restrict__ v,
    float* __restrict__ xcat) {
  const int i = blockIdx.x, h = blockIdx.y, t = threadIdx.x;
  __shared__ float wsh[CAP];
  __shared__ int   jsh[CAP];
  __shared__ float wsum_sh;

  const int c = cnt[i];
  const int* cl = cols + (size_t)i * CAP;
  const float* s2h = s2 + (size_t)h * N;
  const float si = s1[(size_t)h * N + i];

  if (t < 64) {
    float mxl = -INFINITY;
    for (int e = t; e < c; e += 64) {
      float val = si + s2h[cl[e]];
      val = val >= 0.f ? val : ALPHA * val;
      mxl = fmaxf(mxl, val);
    }
#pragma unroll
    for (int off = 32; off; off >>= 1) mxl = fmaxf(mxl, __shfl_xor(mxl, off, 64));
    float wsl = 0.f;
    for (int e = t; e < c; e += 64) {
      int j = cl[e];
      float val = si + s2h[j];
      val = val >= 0.f ? val : ALPHA * val;
      float wv = expf(val - mxl);
      wsh[e] = wv;
      jsh[e] = j;
      wsl += wv;
    }
#pragma unroll
    for (int off = 32; off; off >>= 1) wsl += __shfl_xor(wsl, off, 64);
    if (t == 0) wsum_sh = wsl;
  }
  __syncthreads();

  const float* WhH = Wh + (size_t)h * N * HID;
  float acc = 0.f;
  for (int e = 0; e < c; ++e)
    acc += wsh[e] * WhH[(size_t)jsh[e] * HID + t];

  float hp = acc / wsum_sh;
  float sc = g[t] * rsqrtf(v[t] + EPS);
  float o = (hp - m[t]) * sc + b[t];
  xcat[(size_t)i * (NHEADS * HID) + h * HID + t] = fmaxf(o, 0.f);
}

// ------------------------------- support = xcat @ gc_w  ([N,1024]x[1024,40])
// thread = (row, 4-col group); float4 on both operands (gc_w class dim contiguous)
__global__ __launch_bounds__(256) void support_kernel(
    const float* __restrict__ xcat, const float* __restrict__ gcw,
    float* __restrict__ sup) {
  int gid = blockIdx.x * 256 + threadIdx.x;   // < N*10 exactly
  int row = gid / 10;
  int cg  = gid - row * 10;
  int c0  = cg * 4;
  const float* xr = xcat + (size_t)row * (NHEADS * HID);
  float a0 = 0.f, a1 = 0.f, a2 = 0.f, a3 = 0.f;
  for (int k = 0; k < NHEADS * HID; k += 4) {
    float4 xv = *(const float4*)(xr + k);
    float4 w0 = *(const float4*)(gcw + (size_t)(k + 0) * NCLASS + c0);
    float4 w1 = *(const float4*)(gcw + (size_t)(k + 1) * NCLASS + c0);
    float4 w2 = *(const float4*)(gcw + (size_t)(k + 2) * NCLASS + c0);
    float4 w3 = *(const float4*)(gcw + (size_t)(k + 3) * NCLASS + c0);
    a0 += xv.x * w0.x + xv.y * w1.x + xv.z * w2.x + xv.w * w3.x;
    a1 += xv.x * w0.y + xv.y * w1.y + xv.z * w2.y + xv.w * w3.y;
    a2 += xv.x * w0.z + xv.y * w1.z + xv.z * w2.z + xv.w * w3.z;
    a3 += xv.x * w0.w + xv.y * w1.w + xv.z * w2.w + xv.w * w3.w;
  }
  float4 o; o.x = a0; o.y = a1; o.z = a2; o.w = a3;
  *(float4*)(sup + (size_t)row * NCLASS + c0) = o;
}

// --------- out = log_softmax((0.5*A@sup + sup)/1.5 + gc_b), one wave/row
__global__ __launch_bounds__(64) void final_kernel(
    const float* __restrict__ sup,
    const int* __restrict__ cols, const float* __restrict__ vals,
    const int* __restrict__ cnt, const float* __restrict__ gcb,
    float* __restrict__ out) {
  const int i = blockIdx.x, t = threadIdx.x;
  const bool act = t < NCLASS;
  const int c = cnt[i];
  const int* cl = cols + (size_t)i * CAP;
  const float* vl = vals + (size_t)i * CAP;
  float s = act ? sup[(size_t)i * NCLASS + t] : 0.f;
  float agg = 0.f;
  for (int e = 0; e < c; ++e) {
    int j = cl[e];
    float a = vl[e];
    if (act) agg += a * sup[(size_t)j * NCLASS + t];
  }
  float o = act ? ((0.5f * agg + s) * (1.f / 1.5f) + gcb[t]) : -INFINITY;
  float mx = o;
#pragma unroll
  for (int off = 32; off; off >>= 1) mx = fmaxf(mx, __shfl_xor(mx, off, 64));
  float ex = act ? expf(o - mx) : 0.f;
#pragma unroll
  for (int off = 32; off; off >>= 1) ex += __shfl_xor(ex, off, 64);
  if (act) out[(size_t)i * NCLASS + t] = o - mx - logf(ex);
}

// -------------------------------------------------------------------------
extern "C" void kernel_launch(void* const* d_in, const int* in_sizes, int n_in,
                              void* d_out, int out_size, void* d_ws, size_t ws_size,
                              hipStream_t stream) {
  const float* x     = (const float*)d_in[0];
  const float* adj   = (const float*)d_in[1];
  const float* W_att = (const float*)d_in[2];
  const float* a_src = (const float*)d_in[3];
  const float* a_dst = (const float*)d_in[4];
  const float* bn0_g = (const float*)d_in[5];
  const float* bn0_b = (const float*)d_in[6];
  const float* bn0_m = (const float*)d_in[7];
  const float* bn0_v = (const float*)d_in[8];
  const float* bn1_g = (const float*)d_in[9];
  const float* bn1_b = (const float*)d_in[10];
  const float* bn1_m = (const float*)d_in[11];
  const float* bn1_v = (const float*)d_in[12];
  const float* gc_w  = (const float*)d_in[13];
  const float* gc_b  = (const float*)d_in[14];
  float* out = (float*)d_out;
  (void)in_sizes; (void)n_in; (void)out_size; (void)ws_size;

  char* w = (char*)d_ws;
  float* xn   = (float*)w; w += (size_t)N * NFEAT * 4;
  float* Wh   = (float*)w; w += (size_t)NHEADS * N * HID * 4;
  float* s1   = (float*)w; w += (size_t)NHEADS * N * 4;
  float* s2   = (float*)w; w += (size_t)NHEADS * N * 4;
  float* xcat = (float*)w; w += (size_t)N * NHEADS * HID * 4;
  float* sup  = (float*)w; w += (size_t)N * NCLASS * 4;
  float* vals = (float*)w; w += (size_t)N * CAP * 4;
  int*   cols = (int*)w;   w += (size_t)N * CAP * 4;
  int*   cnt  = (int*)w;   w += (size_t)N * 4;

  bn0_kernel<<<dim3((N * NFEAT + 255) / 256), dim3(256), 0, stream>>>(
      x, bn0_g, bn0_b, bn0_m, bn0_v, xn);
  build_ell<<<dim3(N), dim3(256), 0, stream>>>(adj, cols, vals, cnt);
  gemm_wh<<<dim3(HID / 64, N / 64, NHEADS), dim3(256), 0, stream>>>(
      xn, W_att, Wh);
  score_kernel<<<dim3(NHEADS * N / 4), dim3(256), 0, stream>>>(
      Wh, a_src, a_dst, s1, s2);
  attn_kernel<<<dim3(N, NHEADS), dim3(128), 0, stream>>>(
      Wh, s1, s2, cols, cnt, bn1_g, bn1_b, bn1_m, bn1_v, xcat);
  support_kernel<<<dim3(N * 10 / 256), dim3(256), 0, stream>>>(
      xcat, gc_w, sup);
  final_kernel<<<dim3(N), dim3(64), 0, stream>>>(
      sup, cols, vals, cnt, gc_b, out);
}

// Round 3
// 389.962 us; speedup vs baseline: 1.0676x; 1.0676x over previous
//
#include <hip/hip_runtime.h>
#include <math.h>

#define N      6144
#define NFEAT  128
#define HID    128
#define NHEADS 8
#define NCLASS 40
#define CAP    96        // ELL capacity per row; mean degree ~13
#define EPS    1e-5f
#define ALPHA  0.2f

typedef short bf16x8 __attribute__((ext_vector_type(8)));
typedef float f32x4  __attribute__((ext_vector_type(4)));

__device__ inline float bf2f(unsigned short u) {
  unsigned int x = ((unsigned int)u) << 16;
  return __builtin_bit_cast(float, x);
}
__device__ inline unsigned short f2bf(float f) {
  unsigned int x = __builtin_bit_cast(unsigned int, f);
  x += 0x7fffu + ((x >> 16) & 1u);          // round-to-nearest-even
  return (unsigned short)(x >> 16);
}

// ---------------- prep: BN0 + bf16 cast of x; W transpose + bf16 cast ----
// xb[i][k] = bf16((x-m)*g/sqrt(v+eps)+b);  wbt[h][n][k] = bf16(W[h][k][n])
__global__ __launch_bounds__(256) void prep_kernel(
    const float* __restrict__ x,
    const float* __restrict__ g, const float* __restrict__ b,
    const float* __restrict__ m, const float* __restrict__ v,
    const float* __restrict__ Wall,
    unsigned short* __restrict__ xb, unsigned short* __restrict__ wbt) {
  int idx = blockIdx.x * 256 + threadIdx.x;
  if (idx < N * NFEAT) {
    int c = idx & (NFEAT - 1);
    float sc = g[c] * rsqrtf(v[c] + EPS);
    xb[idx] = f2bf((x[idx] - m[c]) * sc + b[c]);
  } else {
    int t = idx - N * NFEAT;            // t indexes wbt [h][n][k]
    int h = t >> 14, nk = t & 16383, n = nk >> 7, k = nk & 127;
    wbt[t] = f2bf(Wall[(h << 14) + (k << 7) + n]);
  }
}

// ----------------------------------------------- ELL build from dense adj
__global__ __launch_bounds__(256) void build_ell(
    const float* __restrict__ adj,
    int* __restrict__ cols, float* __restrict__ vals, int* __restrict__ cnt) {
  __shared__ int scnt;
  const int i = blockIdx.x;
  if (threadIdx.x == 0) scnt = 0;
  __syncthreads();
  const float* row = adj + (size_t)i * N;
  for (int j4 = threadIdx.x * 4; j4 < N; j4 += 1024) {
    float4 a = *(const float4*)(row + j4);
#pragma unroll
    for (int u = 0; u < 4; ++u) {
      float av = (u == 0) ? a.x : (u == 1) ? a.y : (u == 2) ? a.z : a.w;
      if (av > 0.f) {
        int s = atomicAdd(&scnt, 1);
        if (s < CAP) {
          cols[(size_t)i * CAP + s] = j4 + u;
          vals[(size_t)i * CAP + s] = av;
        }
      }
    }
  }
  __syncthreads();
  if (threadIdx.x == 0) cnt[i] = min(scnt, CAP);
}

// ---------------- Whb[h] = xb @ W[h]  via bf16 MFMA, frags from global ---
// block = 256 thr = 4 waves (2x2); wave computes 64x64; K=128 in 4 MFMA steps.
__global__ __launch_bounds__(256) void gemm_wh_mfma(
    const unsigned short* __restrict__ xb,   // [N][128] bf16
    const unsigned short* __restrict__ wbt,  // [h][n][k] bf16
    unsigned short* __restrict__ whb) {      // [h][N][128] bf16
  const int h   = blockIdx.y;
  const int wid = threadIdx.x >> 6, l = threadIdx.x & 63;
  const int rb  = blockIdx.x * 128 + (wid >> 1) * 64;
  const int cb  = (wid & 1) * 64;
  const int lm  = l & 15, lq = l >> 4;
  const unsigned short* B = wbt + h * HID * NFEAT;
  f32x4 acc[4][4] = {};
#pragma unroll
  for (int kk = 0; kk < 128; kk += 32) {
    bf16x8 af[4], bfr[4];
#pragma unroll
    for (int mt = 0; mt < 4; ++mt)
      af[mt] = *(const bf16x8*)(xb + (size_t)(rb + mt * 16 + lm) * NFEAT + kk + lq * 8);
#pragma unroll
    for (int nt = 0; nt < 4; ++nt)
      bfr[nt] = *(const bf16x8*)(B + (size_t)(cb + nt * 16 + lm) * NFEAT + kk + lq * 8);
#pragma unroll
    for (int mt = 0; mt < 4; ++mt)
#pragma unroll
      for (int nt = 0; nt < 4; ++nt)
        acc[mt][nt] = __builtin_amdgcn_mfma_f32_16x16x32_bf16(
            af[mt], bfr[nt], acc[mt][nt], 0, 0, 0);
  }
  unsigned short* C = whb + (size_t)h * N * HID;
#pragma unroll
  for (int mt = 0; mt < 4; ++mt)
#pragma unroll
    for (int nt = 0; nt < 4; ++nt)
#pragma unroll
      for (int r = 0; r < 4; ++r)
        C[(size_t)(rb + mt * 16 + lq * 4 + r) * HID + cb + nt * 16 + lm] =
            f2bf(acc[mt][nt][r]);
}

// ------------------------------- s1/s2 = Whb · a_src / a_dst, wave per row
__global__ __launch_bounds__(256) void score_kernel(
    const unsigned short* __restrict__ whb,
    const float* __restrict__ a_src, const float* __restrict__ a_dst,
    float* __restrict__ s1, float* __restrict__ s2) {
  int gw = (blockIdx.x * 256 + threadIdx.x) >> 6;   // (h, r)
  int lane = threadIdx.x & 63;
  int h = gw / N;
  const unsigned short* row = whb + (size_t)gw * HID + lane * 2;
  unsigned int u = *(const unsigned int*)row;
  float w0 = bf2f((unsigned short)(u & 0xffff));
  float w1 = bf2f((unsigned short)(u >> 16));
  const float* as = a_src + h * HID + lane * 2;
  const float* ad = a_dst + h * HID + lane * 2;
  float p1 = w0 * as[0] + w1 * as[1];
  float p2 = w0 * ad[0] + w1 * ad[1];
#pragma unroll
  for (int off = 32; off; off >>= 1) {
    p1 += __shfl_xor(p1, off, 64);
    p2 += __shfl_xor(p2, off, 64);
  }
  if (lane == 0) { s1[gw] = p1; s2[gw] = p2; }
}

// ---------------- attention softmax + aggregate + BN1 + ReLU -> xcat -----
__global__ __launch_bounds__(128) void attn_kernel(
    const unsigned short* __restrict__ whb,
    const float* __restrict__ s1, const float* __restrict__ s2,
    const int* __restrict__ cols, const int* __restrict__ cnt,
    const float* __restrict__ g, const float* __restrict__ b,
    const float* __restrict__ m, const float* __restrict__ v,
    float* __restrict__ xcat) {
  const int i = blockIdx.x, h = blockIdx.y, t = threadIdx.x;
  __shared__ float wsh[CAP + 8];
  __shared__ int   jsh[CAP + 8];
  __shared__ float wsum_sh;

  const int c = cnt[i];
  const int* cl = cols + (size_t)i * CAP;
  const float* s2h = s2 + (size_t)h * N;
  const float si = s1[(size_t)h * N + i];

  if (t < 64) {
    float mxl = -INFINITY;
    for (int e = t; e < c; e += 64) {
      float val = si + s2h[cl[e]];
      val = val >= 0.f ? val : ALPHA * val;
      mxl = fmaxf(mxl, val);
    }
#pragma unroll
    for (int off = 32; off; off >>= 1) mxl = fmaxf(mxl, __shfl_xor(mxl, off, 64));
    float wsl = 0.f;
    for (int e = t; e < c; e += 64) {
      int j = cl[e];
      float val = si + s2h[j];
      val = val >= 0.f ? val : ALPHA * val;
      float wv = expf(val - mxl);
      wsh[e] = wv; jsh[e] = j;
      wsl += wv;
    }
#pragma unroll
    for (int off = 32; off; off >>= 1) wsl += __shfl_xor(wsl, off, 64);
    if (t == 0) wsum_sh = wsl;
    for (int e = c + t; e < c + 8; e += 64) { wsh[e] = 0.f; jsh[e] = 0; }
  }
  __syncthreads();

  const unsigned short* WhH = whb + (size_t)h * N * HID;
  float acc = 0.f;
  for (int e0 = 0; e0 < c; e0 += 8) {
#pragma unroll
    for (int u = 0; u < 8; ++u)      // zero-padded: no predication, 8-wide ILP
      acc += wsh[e0 + u] * bf2f(WhH[(size_t)jsh[e0 + u] * HID + t]);
  }

  float hp = acc / wsum_sh;
  float sc = g[t] * rsqrtf(v[t] + EPS);
  float o = (hp - m[t]) * sc + b[t];
  xcat[(size_t)i * (NHEADS * HID) + h * HID + t] = fmaxf(o, 0.f);
}

// ---------------- support = xcat @ gc_w; wave = 2 rows, lane = class -----
__global__ __launch_bounds__(256) void support_kernel(
    const float* __restrict__ xcat, const float* __restrict__ gcw,
    float* __restrict__ sup) {
  int wave = (blockIdx.x * 256 + threadIdx.x) >> 6;   // 0..3071
  int lane = threadIdx.x & 63;
  int cc = lane < NCLASS ? lane : NCLASS - 1;
  const float* x0 = xcat + (size_t)(wave * 2 + 0) * (NHEADS * HID);
  const float* x1 = xcat + (size_t)(wave * 2 + 1) * (NHEADS * HID);
  float a0 = 0.f, a1 = 0.f;
#pragma unroll 4
  for (int k = 0; k < NHEADS * HID; k += 4) {
    float4 v0 = *(const float4*)(x0 + k);          // broadcast
    float4 v1 = *(const float4*)(x1 + k);
    float w0 = gcw[(size_t)(k + 0) * NCLASS + cc];
    float w1 = gcw[(size_t)(k + 1) * NCLASS + cc];
    float w2 = gcw[(size_t)(k + 2) * NCLASS + cc];
    float w3 = gcw[(size_t)(k + 3) * NCLASS + cc];
    a0 += v0.x * w0 + v0.y * w1 + v0.z * w2 + v0.w * w3;
    a1 += v1.x * w0 + v1.y * w1 + v1.z * w2 + v1.w * w3;
  }
  if (lane < NCLASS) {
    sup[(size_t)(wave * 2 + 0) * NCLASS + lane] = a0;
    sup[(size_t)(wave * 2 + 1) * NCLASS + lane] = a1;
  }
}

// --------- out = log_softmax((0.5*A@sup + sup)/1.5 + gc_b), wave per row -
__global__ __launch_bounds__(64) void final_kernel(
    const float* __restrict__ sup,
    const int* __restrict__ cols, const float* __restrict__ vals,
    const int* __restrict__ cnt, const float* __restrict__ gcb,
    float* __restrict__ out) {
  const int i = blockIdx.x, t = threadIdx.x;
  const bool act = t < NCLASS;
  const int c = cnt[i];
  const int* cl = cols + (size_t)i * CAP;
  const float* vl = vals + (size_t)i * CAP;
  float s = act ? sup[(size_t)i * NCLASS + t] : 0.f;
  float agg = 0.f;
  for (int e = 0; e < c; ++e) {
    int j = cl[e];
    float a = vl[e];
    if (act) agg += a * sup[(size_t)j * NCLASS + t];
  }
  float o = act ? ((0.5f * agg + s) * (1.f / 1.5f) + gcb[t]) : -INFINITY;
  float mx = o;
#pragma unroll
  for (int off = 32; off; off >>= 1) mx = fmaxf(mx, __shfl_xor(mx, off, 64));
  float ex = act ? expf(o - mx) : 0.f;
#pragma unroll
  for (int off = 32; off; off >>= 1) ex += __shfl_xor(ex, off, 64);
  if (act) out[(size_t)i * NCLASS + t] = o - mx - logf(ex);
}

// -------------------------------------------------------------------------
extern "C" void kernel_launch(void* const* d_in, const int* in_sizes, int n_in,
                              void* d_out, int out_size, void* d_ws, size_t ws_size,
                              hipStream_t stream) {
  const float* x     = (const float*)d_in[0];
  const float* adj   = (const float*)d_in[1];
  const float* W_att = (const float*)d_in[2];
  const float* a_src = (const float*)d_in[3];
  const float* a_dst = (const float*)d_in[4];
  const float* bn0_g = (const float*)d_in[5];
  const float* bn0_b = (const float*)d_in[6];
  const float* bn0_m = (const float*)d_in[7];
  const float* bn0_v = (const float*)d_in[8];
  const float* bn1_g = (const float*)d_in[9];
  const float* bn1_b = (const float*)d_in[10];
  const float* bn1_m = (const float*)d_in[11];
  const float* bn1_v = (const float*)d_in[12];
  const float* gc_w  = (const float*)d_in[13];
  const float* gc_b  = (const float*)d_in[14];
  float* out = (float*)d_out;
  (void)in_sizes; (void)n_in; (void)out_size; (void)ws_size;

  char* w = (char*)d_ws;
  unsigned short* xb  = (unsigned short*)w; w += (size_t)N * NFEAT * 2;
  unsigned short* wbt = (unsigned short*)w; w += (size_t)NHEADS * NFEAT * HID * 2;
  unsigned short* whb = (unsigned short*)w; w += (size_t)NHEADS * N * HID * 2;
  float* s1   = (float*)w; w += (size_t)NHEADS * N * 4;
  float* s2   = (float*)w; w += (size_t)NHEADS * N * 4;
  float* xcat = (float*)w; w += (size_t)N * NHEADS * HID * 4;
  float* sup  = (float*)w; w += (size_t)N * NCLASS * 4;
  float* vals = (float*)w; w += (size_t)N * CAP * 4;
  int*   cols = (int*)w;   w += (size_t)N * CAP * 4;
  int*   cnt  = (int*)w;   w += (size_t)N * 4;

  prep_kernel<<<dim3((N * NFEAT + NHEADS * NFEAT * HID) / 256), dim3(256), 0, stream>>>(
      x, bn0_g, bn0_b, bn0_m, bn0_v, W_att, xb, wbt);
  build_ell<<<dim3(N), dim3(256), 0, stream>>>(adj, cols, vals, cnt);
  gemm_wh_mfma<<<dim3(N / 128, NHEADS), dim3(256), 0, stream>>>(xb, wbt, whb);
  score_kernel<<<dim3(NHEADS * N / 4), dim3(256), 0, stream>>>(
      whb, a_src, a_dst, s1, s2);
  attn_kernel<<<dim3(N, NHEADS), dim3(128), 0, stream>>>(
      whb, s1, s2, cols, cnt, bn1_g, bn1_b, bn1_m, bn1_v, xcat);
  // (N/2 rows-per-wave pairs) * 64 lanes / 256 threads = 768 blocks = 3072 waves
  support_kernel<<<dim3((N / 2) * 64 / 256), dim3(256), 0, stream>>>(
      xcat, gc_w, sup);
  final_kernel<<<dim3(N), dim3(64), 0, stream>>>(
      sup, cols, vals, cnt, gc_b, out);
}

// Round 4
// 358.723 us; speedup vs baseline: 1.1606x; 1.0871x over previous
//
#include <hip/hip_runtime.h>
#include <math.h>

#define N      6144
#define NFEAT  128
#define HID    128
#define NHEADS 8
#define NCLASS 40
#define CAP    96        // ELL capacity per row; mean degree ~13
#define EPS    1e-5f
#define ALPHA  0.2f

typedef short bf16x8 __attribute__((ext_vector_type(8)));
typedef float f32x4  __attribute__((ext_vector_type(4)));

__device__ inline float bf2f(unsigned short u) {
  unsigned int x = ((unsigned int)u) << 16;
  return __builtin_bit_cast(float, x);
}
__device__ inline unsigned short f2bf(float f) {
  unsigned int x = __builtin_bit_cast(unsigned int, f);
  x += 0x7fffu + ((x >> 16) & 1u);          // round-to-nearest-even
  return (unsigned short)(x >> 16);
}

// ------- fused: ELL build (blocks 0..N-1) + BN0/W prep (blocks N..) -------
__global__ __launch_bounds__(256) void prep_ell_kernel(
    const float* __restrict__ adj,
    int* __restrict__ cols, float* __restrict__ vals, int* __restrict__ cnt,
    const float* __restrict__ x,
    const float* __restrict__ g, const float* __restrict__ b,
    const float* __restrict__ m, const float* __restrict__ v,
    const float* __restrict__ Wall,
    unsigned short* __restrict__ xb, unsigned short* __restrict__ wbt) {
  __shared__ int scnt;
  if (blockIdx.x < N) {
    const int i = blockIdx.x;
    if (threadIdx.x == 0) scnt = 0;
    __syncthreads();
    const float* row = adj + (size_t)i * N;
    for (int j4 = threadIdx.x * 4; j4 < N; j4 += 1024) {
      float4 a = *(const float4*)(row + j4);
#pragma unroll
      for (int u = 0; u < 4; ++u) {
        float av = (u == 0) ? a.x : (u == 1) ? a.y : (u == 2) ? a.z : a.w;
        if (av > 0.f) {
          int s = atomicAdd(&scnt, 1);
          if (s < CAP) {
            cols[(size_t)i * CAP + s] = j4 + u;
            vals[(size_t)i * CAP + s] = av;
          }
        }
      }
    }
    __syncthreads();
    if (threadIdx.x == 0) cnt[i] = min(scnt, CAP);
  } else {
    int idx = (blockIdx.x - N) * 256 + threadIdx.x;
    if (idx < N * NFEAT) {
      int c = idx & (NFEAT - 1);
      float sc = g[c] * rsqrtf(v[c] + EPS);
      xb[idx] = f2bf((x[idx] - m[c]) * sc + b[c]);
    } else {
      int t = idx - N * NFEAT;            // t indexes wbt [h][n][k]
      int h = t >> 14, nk = t & 16383, n = nk >> 7, k = nk & 127;
      wbt[t] = f2bf(Wall[(h << 14) + (k << 7) + n]);
    }
  }
}

// ------- GEMM (bf16 MFMA, LDS-staged) + fused score epilogue --------------
// block = 256 thr (4 waves). Tile: 64 rows x 128 cols (one head). Wave w
// owns cols w*32..w*32+31. Writes whc[N][1024] (head-concat layout) and
// s1/s2 from the fp32 accumulators.
__global__ __launch_bounds__(256) void gemm_score(
    const unsigned short* __restrict__ xb,   // [N][128] bf16
    const unsigned short* __restrict__ wbt,  // [h][n][k] bf16 (W^T per head)
    const float* __restrict__ a_src, const float* __restrict__ a_dst,
    unsigned short* __restrict__ whc,        // [N][NHEADS*HID] bf16
    float* __restrict__ s1, float* __restrict__ s2) {
  const int h  = blockIdx.y;
  const int rb = blockIdx.x * 64;
  __shared__ unsigned short As[64][136];     // +8 pad: 16B-aligned, 2-way free
  __shared__ unsigned short Bs[128][136];
  __shared__ float s1p[64], s2p[64];
  const int tid = threadIdx.x;

  if (tid < 64) { s1p[tid] = 0.f; s2p[tid] = 0.f; }
#pragma unroll
  for (int r = 0; r < 4; ++r) {              // stage A: 64x128, coalesced
    int chunk = tid + r * 256;
    int row = chunk >> 4, c8 = (chunk & 15) * 8;
    *(uint4*)&As[row][c8] = *(const uint4*)(xb + (size_t)(rb + row) * NFEAT + c8);
  }
  const unsigned short* W = wbt + h * (HID * NFEAT);
#pragma unroll
  for (int r = 0; r < 8; ++r) {              // stage B: 128x128, coalesced
    int chunk = tid + r * 256;
    int row = chunk >> 4, c8 = (chunk & 15) * 8;
    *(uint4*)&Bs[row][c8] = *(const uint4*)(W + (size_t)row * NFEAT + c8);
  }
  __syncthreads();

  const int wid = tid >> 6, l = tid & 63, lm = l & 15, lq = l >> 4;
  const int cw = wid * 32;
  f32x4 acc[4][2] = {};
#pragma unroll
  for (int kk = 0; kk < NFEAT; kk += 32) {
    bf16x8 af[4], bfr[2];
#pragma unroll
    for (int mt = 0; mt < 4; ++mt)
      af[mt] = *(const bf16x8*)&As[mt * 16 + lm][kk + lq * 8];
#pragma unroll
    for (int nt = 0; nt < 2; ++nt)
      bfr[nt] = *(const bf16x8*)&Bs[cw + nt * 16 + lm][kk + lq * 8];
#pragma unroll
    for (int mt = 0; mt < 4; ++mt)
#pragma unroll
      for (int nt = 0; nt < 2; ++nt)
        acc[mt][nt] = __builtin_amdgcn_mfma_f32_16x16x32_bf16(
            af[mt], bfr[nt], acc[mt][nt], 0, 0, 0);
  }

  // C store: whc[row][h*128 + col]
  unsigned short* C = whc + (size_t)h * HID;
#pragma unroll
  for (int mt = 0; mt < 4; ++mt)
#pragma unroll
    for (int nt = 0; nt < 2; ++nt)
#pragma unroll
      for (int r = 0; r < 4; ++r)
        C[(size_t)(rb + mt * 16 + lq * 4 + r) * (NHEADS * HID)
          + cw + nt * 16 + lm] = f2bf(acc[mt][nt][r]);

  // fused score: s1[row] += sum_col acc*a_src (this wave's 32 cols)
  const float as0 = a_src[h * HID + cw + lm];
  const float as1 = a_src[h * HID + cw + 16 + lm];
  const float ad0 = a_dst[h * HID + cw + lm];
  const float ad1 = a_dst[h * HID + cw + 16 + lm];
#pragma unroll
  for (int mt = 0; mt < 4; ++mt)
#pragma unroll
    for (int r = 0; r < 4; ++r) {
      float p1 = acc[mt][0][r] * as0 + acc[mt][1][r] * as1;
      float p2 = acc[mt][0][r] * ad0 + acc[mt][1][r] * ad1;
#pragma unroll
      for (int off = 1; off < 16; off <<= 1) {
        p1 += __shfl_xor(p1, off, 64);
        p2 += __shfl_xor(p2, off, 64);
      }
      if (lm == 0) {
        atomicAdd(&s1p[mt * 16 + lq * 4 + r], p1);
        atomicAdd(&s2p[mt * 16 + lq * 4 + r], p2);
      }
    }
  __syncthreads();
  if (tid < 64) {
    s1[(size_t)h * N + rb + tid] = s1p[tid];
    s2[(size_t)h * N + rb + tid] = s2p[tid];
  }
}

// ------- attention: one block per row, all 8 heads; softmax + aggregate +
// BN1 + ReLU -> xcat[i][1024] ---------------------------------------------
__global__ __launch_bounds__(256) void attn_kernel(
    const unsigned short* __restrict__ whc,  // [N][1024]
    const float* __restrict__ s1, const float* __restrict__ s2,
    const int* __restrict__ cols, const int* __restrict__ cnt,
    const float* __restrict__ g, const float* __restrict__ b,
    const float* __restrict__ m, const float* __restrict__ v,
    float* __restrict__ xcat) {
  const int i = blockIdx.x, t = threadIdx.x;
  __shared__ int   jsh[CAP + 4];
  __shared__ float wsh[NHEADS][CAP + 4];
  __shared__ float ssum[NHEADS];

  const int c = cnt[i];
  if (t < CAP) jsh[t] = (t < c) ? cols[(size_t)i * CAP + t] : 0;
  else if (t < CAP + 4) jsh[t] = 0;
  if (t < 32) wsh[t >> 2][c + (t & 3)] = 0.f;   // zero 4-pad for all heads
  __syncthreads();

  if (t < 128) {                       // 16 threads per head
    const int h = t >> 4, u = t & 15;
    const float si = s1[(size_t)h * N + i];
    const float* s2h = s2 + (size_t)h * N;
    float mx = -INFINITY;
    for (int e = u; e < c; e += 16) {
      float val = si + s2h[jsh[e]];
      val = val >= 0.f ? val : ALPHA * val;
      mx = fmaxf(mx, val);
    }
#pragma unroll
    for (int off = 1; off < 16; off <<= 1) mx = fmaxf(mx, __shfl_xor(mx, off, 64));
    float sm = 0.f;
    for (int e = u; e < c; e += 16) {
      float val = si + s2h[jsh[e]];
      val = val >= 0.f ? val : ALPHA * val;
      float wv = expf(val - mx);
      wsh[h][e] = wv;
      sm += wv;
    }
#pragma unroll
    for (int off = 1; off < 16; off <<= 1) sm += __shfl_xor(sm, off, 64);
    if (u == 0) ssum[h] = sm;
  }
  __syncthreads();

  // aggregate: thread t covers features {2t,2t+1} and {512+2t, 512+2t+1}
  const int h0 = t >> 6;               // head of chunk-0 pair (wave-uniform)
  const int h1 = 4 + (t >> 6);         // head of chunk-1 pair
  float a00 = 0.f, a01 = 0.f, a10 = 0.f, a11 = 0.f;
  for (int e = 0; e < c; e += 4) {
#pragma unroll
    for (int u2 = 0; u2 < 4; ++u2) {
      const int j = jsh[e + u2];
      const unsigned int* row = (const unsigned int*)(whc + (size_t)j * (NHEADS * HID));
      const float w0 = wsh[h0][e + u2];
      const float w1 = wsh[h1][e + u2];
      unsigned int p0 = row[t];          // features 2t, 2t+1
      unsigned int p1 = row[256 + t];    // features 512+2t, 512+2t+1
      a00 += w0 * bf2f((unsigned short)(p0 & 0xffff));
      a01 += w0 * bf2f((unsigned short)(p0 >> 16));
      a10 += w1 * bf2f((unsigned short)(p1 & 0xffff));
      a11 += w1 * bf2f((unsigned short)(p1 >> 16));
    }
  }

  const int ch0 = (2 * t) & 127, ch1 = ch0 + 1;   // same channels both chunks
  const float sc0 = g[ch0] * rsqrtf(v[ch0] + EPS);
  const float sc1 = g[ch1] * rsqrtf(v[ch1] + EPS);
  const float m0 = m[ch0], m1 = m[ch1], b0 = b[ch0], b1 = b[ch1];
  const float is0 = ssum[h0], is1 = ssum[h1];
  float2 o0, o1;
  o0.x = fmaxf((a00 / is0 - m0) * sc0 + b0, 0.f);
  o0.y = fmaxf((a01 / is0 - m1) * sc1 + b1, 0.f);
  o1.x = fmaxf((a10 / is1 - m0) * sc0 + b0, 0.f);
  o1.y = fmaxf((a11 / is1 - m1) * sc1 + b1, 0.f);
  float* xr = xcat + (size_t)i * (NHEADS * HID);
  *(float2*)(xr + 2 * t) = o0;
  *(float2*)(xr + 512 + 2 * t) = o1;
}

// ---------------- support = xcat @ gc_w; wave = 2 rows, lane = class -----
__global__ __launch_bounds__(256) void support_kernel(
    const float* __restrict__ xcat, const float* __restrict__ gcw,
    float* __restrict__ sup) {
  int wave = (blockIdx.x * 256 + threadIdx.x) >> 6;   // 0..3071
  int lane = threadIdx.x & 63;
  int cc = lane < NCLASS ? lane : NCLASS - 1;
  const float* x0 = xcat + (size_t)(wave * 2 + 0) * (NHEADS * HID);
  const float* x1 = xcat + (size_t)(wave * 2 + 1) * (NHEADS * HID);
  float a0 = 0.f, a1 = 0.f;
#pragma unroll 4
  for (int k = 0; k < NHEADS * HID; k += 4) {
    float4 v0 = *(const float4*)(x0 + k);          // broadcast
    float4 v1 = *(const float4*)(x1 + k);
    float w0 = gcw[(size_t)(k + 0) * NCLASS + cc];
    float w1 = gcw[(size_t)(k + 1) * NCLASS + cc];
    float w2 = gcw[(size_t)(k + 2) * NCLASS + cc];
    float w3 = gcw[(size_t)(k + 3) * NCLASS + cc];
    a0 += v0.x * w0 + v0.y * w1 + v0.z * w2 + v0.w * w3;
    a1 += v1.x * w0 + v1.y * w1 + v1.z * w2 + v1.w * w3;
  }
  if (lane < NCLASS) {
    sup[(size_t)(wave * 2 + 0) * NCLASS + lane] = a0;
    sup[(size_t)(wave * 2 + 1) * NCLASS + lane] = a1;
  }
}

// --------- out = log_softmax((0.5*A@sup + sup)/1.5 + gc_b), wave per row -
__global__ __launch_bounds__(64) void final_kernel(
    const float* __restrict__ sup,
    const int* __restrict__ cols, const float* __restrict__ vals,
    const int* __restrict__ cnt, const float* __restrict__ gcb,
    float* __restrict__ out) {
  const int i = blockIdx.x, t = threadIdx.x;
  const bool act = t < NCLASS;
  const int c = cnt[i];
  const int* cl = cols + (size_t)i * CAP;
  const float* vl = vals + (size_t)i * CAP;
  float s = act ? sup[(size_t)i * NCLASS + t] : 0.f;
  float agg = 0.f;
  for (int e = 0; e < c; ++e) {
    int j = cl[e];
    float a = vl[e];
    if (act) agg += a * sup[(size_t)j * NCLASS + t];
  }
  float o = act ? ((0.5f * agg + s) * (1.f / 1.5f) + gcb[t]) : -INFINITY;
  float mx = o;
#pragma unroll
  for (int off = 32; off; off >>= 1) mx = fmaxf(mx, __shfl_xor(mx, off, 64));
  float ex = act ? expf(o - mx) : 0.f;
#pragma unroll
  for (int off = 32; off; off >>= 1) ex += __shfl_xor(ex, off, 64);
  if (act) out[(size_t)i * NCLASS + t] = o - mx - logf(ex);
}

// -------------------------------------------------------------------------
extern "C" void kernel_launch(void* const* d_in, const int* in_sizes, int n_in,
                              void* d_out, int out_size, void* d_ws, size_t ws_size,
                              hipStream_t stream) {
  const float* x     = (const float*)d_in[0];
  const float* adj   = (const float*)d_in[1];
  const float* W_att = (const float*)d_in[2];
  const float* a_src = (const float*)d_in[3];
  const float* a_dst = (const float*)d_in[4];
  const float* bn0_g = (const float*)d_in[5];
  const float* bn0_b = (const float*)d_in[6];
  const float* bn0_m = (const float*)d_in[7];
  const float* bn0_v = (const float*)d_in[8];
  const float* bn1_g = (const float*)d_in[9];
  const float* bn1_b = (const float*)d_in[10];
  const float* bn1_m = (const float*)d_in[11];
  const float* bn1_v = (const float*)d_in[12];
  const float* gc_w  = (const float*)d_in[13];
  const float* gc_b  = (const float*)d_in[14];
  float* out = (float*)d_out;
  (void)in_sizes; (void)n_in; (void)out_size; (void)ws_size;

  char* w = (char*)d_ws;
  unsigned short* xb  = (unsigned short*)w; w += (size_t)N * NFEAT * 2;
  unsigned short* wbt = (unsigned short*)w; w += (size_t)NHEADS * NFEAT * HID * 2;
  unsigned short* whc = (unsigned short*)w; w += (size_t)N * NHEADS * HID * 2;
  float* s1   = (float*)w; w += (size_t)NHEADS * N * 4;
  float* s2   = (float*)w; w += (size_t)NHEADS * N * 4;
  float* xcat = (float*)w; w += (size_t)N * NHEADS * HID * 4;
  float* sup  = (float*)w; w += (size_t)N * NCLASS * 4;
  float* vals = (float*)w; w += (size_t)N * CAP * 4;
  int*   cols = (int*)w;   w += (size_t)N * CAP * 4;
  int*   cnt  = (int*)w;   w += (size_t)N * 4;

  const int prep_blocks = (N * NFEAT + NHEADS * NFEAT * HID) / 256;  // 3584
  prep_ell_kernel<<<dim3(N + prep_blocks), dim3(256), 0, stream>>>(
      adj, cols, vals, cnt, x, bn0_g, bn0_b, bn0_m, bn0_v, W_att, xb, wbt);
  gemm_score<<<dim3(N / 64, NHEADS), dim3(256), 0, stream>>>(
      xb, wbt, a_src, a_dst, whc, s1, s2);
  attn_kernel<<<dim3(N), dim3(256), 0, stream>>>(
      whc, s1, s2, cols, cnt, bn1_g, bn1_b, bn1_m, bn1_v, xcat);
  support_kernel<<<dim3((N / 2) * 64 / 256), dim3(256), 0, stream>>>(
      xcat, gc_w, sup);
  final_kernel<<<dim3(N), dim3(64), 0, stream>>>(
      sup, cols, vals, cnt, gc_b, out);
}